// Round 5
// baseline (18143.948 us; speedup 1.0000x reference)
//
#include <hip/hip_runtime.h>
#include <hip/hip_bf16.h>
#include <math.h>
#include <stdint.h>

// ---------- problem constants ----------
#define B_    128
#define S_    512
#define IN_   1024
#define HID_  1024
#define CHI_  0.638f
#define KAPPA_ 0.35f
#define DT_   0.01f
#define CH    32            // timesteps per chunk
#define NCHUNK (S_/CH)      // 16

// output offsets (floats)
#define OUT_H 67108864
#define OUT_C 67239936
#define OUT_Z 67371008

// ---------- ws layout (bytes) ----------
// h/c/o/e state buffers use fragment-major "hF" layout:
//   per group 64KB = 2 planes(rows p*16..p*16+16) x [kq 0..31][lane 0..63][16B]
//   element (r,k): plane=r>>4, 16B-unit = (k>>5)*64 + ((k>>3)&3)*16 + (r&15), byte=(k&7)*2
#define WS_CNT   0                         // 4 groups x 64 arrive flags (u32)
#define WS_HBF   1024                      // h  hF bf16 [4 groups][64KB]
#define WS_CF32  263168                    // c' f32 (chunk-boundary persistence, owner layout)
#define WS_STATE_BYTES 787456              // CNT + HBF + CF32 zeroed at start
#define WS_CBF   787456                    // c~ hF bf16
#define WS_OBF   1049600                   // o  hF bf16
#define WS_EBF   1311744                   // e  hF bf16
#define WS_KP    1573888                   // kap partials [4][32][8] f32 (atomicAdd)
#define WS_WGT   1577984                   // WgT bf16 [4096][2048]
#define WS_EVOT  18355200                  // evoT bf16 [1024][1024]
#define WS_MIRT  20452352                  // mirT bf16 [1024][1024]
#define WS_C1T   22549504                  // c1T bf16 [512][1024]
#define WS_XBF   23598080                  // x chunk bf16 [32*128][1024]
#define WS_GXC   31986688                  // gx chunk bf16 [32][4][4096][32]
// total ~40.4 MB

using s16x8 = __attribute__((ext_vector_type(8))) short;
using s16x4 = __attribute__((ext_vector_type(4))) short;
using f32x4 = __attribute__((ext_vector_type(4))) float;
typedef unsigned long long u64;

static __device__ __forceinline__ short f2bf(float x){
  unsigned int u = __float_as_uint(x);
  u = (u + 0x7FFFu + ((u >> 16) & 1u)) >> 16;
  return (short)u;
}
static __device__ __forceinline__ float b2f(short s){
  return __uint_as_float(((unsigned int)(unsigned short)s) << 16);
}
static __device__ __forceinline__ float sigf(float x){
  return 1.f / (1.f + __expf(-x));
}
static __device__ __forceinline__ float tanhf_(float x){
  return 1.f - 2.f / (__expf(2.f * x) + 1.f);
}
static __device__ __forceinline__ f32x4 mfma16(s16x8 a, s16x8 b, f32x4 c){
  return __builtin_amdgcn_mfma_f32_16x16x32_bf16(a, b, c, 0, 0, 0);
}

// ---------- coherent (device-scope, L2-bypassing) access helpers ----------
static __device__ __forceinline__ u64 ld_coh_u64(const void* p){
  return __hip_atomic_load((const u64*)p, __ATOMIC_RELAXED, __HIP_MEMORY_SCOPE_AGENT);
}
static __device__ __forceinline__ void st_coh_u64(void* p, u64 v){
  __hip_atomic_store((u64*)p, v, __ATOMIC_RELAXED, __HIP_MEMORY_SCOPE_AGENT);
}
static __device__ __forceinline__ void st_coh_f32(float* p, float v){
  __hip_atomic_store(p, v, __ATOMIC_RELAXED, __HIP_MEMORY_SCOPE_AGENT);
}
static __device__ __forceinline__ unsigned ld_coh_u32(const unsigned* p){
  return __hip_atomic_load(p, __ATOMIC_RELAXED, __HIP_MEMORY_SCOPE_AGENT);
}
static __device__ __forceinline__ void st_coh_u32(unsigned* p, unsigned v){
  __hip_atomic_store(p, v, __ATOMIC_RELAXED, __HIP_MEMORY_SCOPE_AGENT);
}
static __device__ __forceinline__ void at_add_f32(float* p, float v){
  __hip_atomic_fetch_add(p, v, __ATOMIC_RELAXED, __HIP_MEMORY_SCOPE_AGENT);
}
static __device__ __forceinline__ s16x8 ld_coh16B(const short* p){
  union { u64 q[2]; s16x8 v; } u;
  u.q[0] = ld_coh_u64(p);
  u.q[1] = ld_coh_u64(p + 4);
  return u.v;
}

// flag barrier: block n stores gen to its own flag; wave0 polls all 64 flags.
static __device__ __forceinline__ void gbar(unsigned* arr, int n, unsigned gen){
  asm volatile("s_waitcnt vmcnt(0)" ::: "memory");
  __syncthreads();
  if (threadIdx.x < 64){
    if (threadIdx.x == 0) st_coh_u32(arr + n, gen);
    unsigned v = ld_coh_u32(arr + threadIdx.x);
    while (!__all(v >= gen)){
      v = ld_coh_u32(arr + threadIdx.x);
    }
  }
  __syncthreads();
}

// ---------- prep kernels ----------
__global__ void transpose_bf(const float* __restrict__ in, short* __restrict__ out,
                             int R, int C){
  __shared__ float tile[32][33];
  int c0 = blockIdx.x * 32, r0 = blockIdx.y * 32;
  int tc = threadIdx.x & 31, tr = threadIdx.x >> 5;   // tr 0..7
  #pragma unroll
  for (int i = 0; i < 4; i++){
    int r = tr + i * 8;
    tile[r][tc] = in[(size_t)(r0 + r) * C + (c0 + tc)];
  }
  __syncthreads();
  #pragma unroll
  for (int i = 0; i < 4; i++){
    int cc = tr + i * 8;
    out[(size_t)(c0 + cc) * R + (r0 + tc)] = f2bf(tile[tc][cc]);
  }
}

__global__ void conv_x(const float* __restrict__ x, short* __restrict__ xbf, int t0){
  int rb = blockIdx.x;                 // rb = tl*128 + b
  int tl = rb >> 7, b = rb & 127;
  const float* src = x + ((size_t)b * S_ + (t0 + tl)) * (size_t)IN_;
  short* dst = xbf + (size_t)rb * IN_;
  int i = threadIdx.x * 4;
  float4 v = *(const float4*)(src + i);
  s16x4 o; o[0]=f2bf(v.x); o[1]=f2bf(v.y); o[2]=f2bf(v.z); o[3]=f2bf(v.w);
  *(s16x4*)(dst + i) = o;
}

// gx chunk GEMM: A = xbf [4096][1024] bf16 (m = tl*128+b), B = WgT[:, 0:1024]
// C written as gxc[tl][g=b>>5][gatecol][b&31] bf16 (group-contiguous lines)
__global__ __launch_bounds__(256, 2) void gemm_gx(const short* __restrict__ Ax,
                                                  const short* __restrict__ wgT,
                                                  short* __restrict__ gxc){
  __shared__ short As[128 * 32];
  __shared__ short Bs[128 * 32];
  const int tid = threadIdx.x, w = tid >> 6, l = tid & 63;
  const int wm = w & 1, wn = w >> 1;
  const int bn = blockIdx.x, bm = blockIdx.y;
  const int lc = l & 15, kg = l >> 4;
  f32x4 acc[4][4];
  #pragma unroll
  for (int i = 0; i < 4; i++)
    #pragma unroll
    for (int j = 0; j < 4; j++) acc[i][j] = f32x4{0.f, 0.f, 0.f, 0.f};

  const int srow = tid >> 1;
  const int so = (tid & 1) * 32;   // byte offset within 64B row
  const short* ga = Ax  + (size_t)(bm * 128 + srow) * 1024 + (so >> 1);
  const short* gb = wgT + (size_t)(bn * 128 + srow) * 2048 + (so >> 1);
  const int sp0 = srow * 64 + ((so)      ^ ((srow & 3) << 4));
  const int sp1 = srow * 64 + ((so + 16) ^ ((srow & 3) << 4));

  uint4 ra0, ra1, rb0, rb1;
  auto LD = [&](int kt){
    ra0 = *(const uint4*)(ga + kt * 32);
    ra1 = *(const uint4*)(ga + kt * 32 + 8);
    rb0 = *(const uint4*)(gb + kt * 32);
    rb1 = *(const uint4*)(gb + kt * 32 + 8);
  };
  LD(0);
  for (int kt = 0; kt < 32; ++kt){
    __syncthreads();
    *(uint4*)((char*)As + sp0) = ra0;
    *(uint4*)((char*)As + sp1) = ra1;
    *(uint4*)((char*)Bs + sp0) = rb0;
    *(uint4*)((char*)Bs + sp1) = rb1;
    __syncthreads();
    if (kt + 1 < 32) LD(kt + 1);
    s16x8 af[4], bfr[4];
    #pragma unroll
    for (int mf = 0; mf < 4; ++mf){
      int row = wm * 64 + mf * 16 + lc;
      af[mf] = *(const s16x8*)((const char*)As + row * 64 + ((kg * 16) ^ ((row & 3) << 4)));
    }
    #pragma unroll
    for (int nf = 0; nf < 4; ++nf){
      int row = wn * 64 + nf * 16 + lc;
      bfr[nf] = *(const s16x8*)((const char*)Bs + row * 64 + ((kg * 16) ^ ((row & 3) << 4)));
    }
    #pragma unroll
    for (int mf = 0; mf < 4; ++mf)
      #pragma unroll
      for (int nf = 0; nf < 4; ++nf)
        acc[mf][nf] = mfma16(af[mf], bfr[nf], acc[mf][nf]);
  }
  // epilogue: gxc[tl=bm][gg][gc][bb]
  #pragma unroll
  for (int mf = 0; mf < 4; ++mf){
    #pragma unroll
    for (int nf = 0; nf < 4; ++nf){
      int b0 = wm * 64 + mf * 16 + kg * 4;
      int gg = b0 >> 5, bb = b0 & 31;
      int gc = bn * 128 + wn * 64 + nf * 16 + lc;
      s16x4 pk;
      #pragma unroll
      for (int r = 0; r < 4; r++) pk[r] = f2bf(acc[mf][nf][r]);
      *(s16x4*)(gxc + (((size_t)bm * 4 + gg) * 4096 + gc) * 32 + bb) = pk;
    }
  }
}

// ---------- zeta ----------
struct cpx { double r, i; };
static __device__ cpx cexp_(cpx z){ double e = exp(z.r); return {e * cos(z.i), e * sin(z.i)}; }
static __device__ cpx xi_(double sr, double si, const float* zw, const float* zp){
  cpx acc{0.0, 0.0};
  for (int i = 0; i < 6; i++){
    double L = 0.2 + 0.1 * i;
    double sw = 1.0 / (1.0 + exp(-(double)zw[i]));
    double sp = 1.0 / (1.0 + exp(-(double)zp[i]));
    cpx t1 = cexp_({-sr * L, -si * L});
    cpx t2 = cexp_({-(1.0 - sr) * L, si * L});
    acc.r += sw * 0.5 * (t1.r + sp * t2.r);
    acc.i += sw * 0.5 * (t1.i + sp * t2.i);
  }
  return acc;
}
__global__ void zeta_k(const float* __restrict__ zw, const float* __restrict__ zp,
                       float* __restrict__ dz){
  if (threadIdx.x == 0 && blockIdx.x == 0){
    cpx a = xi_(0.5, -2.0, zw, zp);
    cpx b = xi_(0.5,  2.0, zw, zp);
    double dr = a.r - b.r, di = a.i - b.i;
    dz[0] = (float)(dr * dr + di * di);
  }
}

// reduce scratch access: 16B-aligned XOR-swizzled f32x4 slots
#define RSLOT(slot, j) ((char*)red + (slot) * 8192 + (size_t)l * 128 + (((j) * 16) ^ ((l & 7) << 4)))

// ---------- persistent scan kernel (one chunk of CH steps) ----------
// 4 groups x 32 batch rows; 64 blocks/group; 512 threads (8 waves); 3 phases/step.
__global__ __launch_bounds__(512, 2) void scan_k(
    const short* __restrict__ wgT, const short* __restrict__ evoT,
    const short* __restrict__ mirT, const short* __restrict__ c1T,
    const short* __restrict__ gxc,
    const float* __restrict__ bg,  const float* __restrict__ evob,
    const float* __restrict__ mirb, const float* __restrict__ cb1,
    const float* __restrict__ cw2, const float* __restrict__ cb2,
    short* __restrict__ hbf, short* __restrict__ cbf, short* __restrict__ obf,
    short* __restrict__ ebf, float* __restrict__ cf32, float* __restrict__ kp,
    unsigned int* __restrict__ cnt, float* __restrict__ dout, int t0)
{
  const int tid = threadIdx.x;
  const int w = tid >> 6, l = tid & 63;
  const int lc = l & 15, kg = l >> 4;
  const int bi = blockIdx.x;
  const int g = bi >> 6, n = bi & 63;
  unsigned* arr = cnt + g * 64;

  __shared__ float red[4][64][32];      // 32KB reduce scratch (XOR-swizzled)
  __shared__ float gatesL[4][32][17];
  __shared__ float eL[32][17];
  __shared__ float kpart[32][4];
  __shared__ float kapL[32];
  __shared__ short stL[32][16];
  __shared__ short oSt[32][16];
  __shared__ float hfL[32][16];

  // hF group bases (shorts)
  const short* hG = hbf + (size_t)g * 32768;
  const short* cG = cbf + (size_t)g * 32768;
  const short* oG = obf + (size_t)g * 32768;
  const short* eG = ebf + (size_t)g * 32768;
  float* kpg = kp + g * 256;            // [32][8]

  // publish offset (shorts): pt in [0,128): rr=pt>>2 row, ci=pt&3 (4-col u64)
  const int pt = tid & 127;
  const int prr = pt >> 2, pci = pt & 3;
  const size_t poff = (size_t)(prr >> 4) * 16384 + (size_t)(n >> 1) * 512
                    + (size_t)(2 * (n & 1) + (pci >> 1)) * 128 + (prr & 15) * 8 + (pci & 1) * 4;

  // owner mapping: thread -> (row = tid&31, colL = tid>>5), col = n*16+colL
  const int orow = tid & 31, ocolL = tid >> 5;
  const int ocol = n * 16 + ocolL;
  const size_t oidx = (size_t)(g * 32 + orow) * HID_ + ocol;
  float c_state = cf32[oidx];
  float o_reg = 0.f;
  float bgv[4];
  #pragma unroll
  for (int q = 0; q < 4; q++) bgv[q] = bg[q * 1024 + ocol];
  const float cb2v = cb2[0];

  // wave-role constant pointers (B operands, normal cached loads)
  const short* bq0 = wgT + (size_t)(0 * 1024 + n * 16 + lc) * 2048 + 1024 + w * 128 + kg * 8;
  const short* bq1 = wgT + (size_t)(1 * 1024 + n * 16 + lc) * 2048 + 1024 + w * 128 + kg * 8;
  const short* bq2 = wgT + (size_t)(2 * 1024 + n * 16 + lc) * 2048 + 1024 + w * 128 + kg * 8;
  const short* bq3 = wgT + (size_t)(3 * 1024 + n * 16 + lc) * 2048 + 1024 + w * 128 + kg * 8;
  const int kh2 = w & 3;
  const short* bevo = evoT + (size_t)(n * 16 + lc) * 1024 + kh2 * 256 + kg * 8;
  const int s_cv = (n >> 1) * 16;
  const short* bcur = c1T + (size_t)(s_cv + lc) * 1024 + kh2 * 256 + kg * 8;
  const short* bmir = mirT + (size_t)(n * 16 + lc) * 1024 + w * 128 + kg * 8;   // 8-wave K-split
  const float ebias = evob[n * 16 + lc];
  const float c1bv = cb1[s_cv + lc], c2wv = cw2[s_cv + lc];
  const float mirbv = mirb[n * 16 + lc];
  const float cvalid = ((lc >> 3) == (n & 1)) ? 1.f : 0.f;

  unsigned gen = (unsigned)t0 * 3;

  for (int lt = 0; lt < CH; ++lt){
    const int t = t0 + lt;

    // gx prefetch (normal loads, group-contiguous layout)
    float gxv[4];
    #pragma unroll
    for (int q = 0; q < 4; q++)
      gxv[q] = b2f(gxc[(((size_t)lt * 4 + g) * 4096 + q * 1024 + ocol) * 32 + orow]);

    // kp re-zero for this step (slot n>>3, by the 8 blocks with n&7==0)
    if ((n & 7) == 0 && tid < 32)
      st_coh_f32(kpg + tid * 8 + (n >> 3), 0.f);

    // ---------- PHASE A: gates = gx + h @ Wh + b; c~, o; publish c~, o ----------
    {
      f32x4 acc[4][2];
      #pragma unroll
      for (int q = 0; q < 4; q++){ acc[q][0] = f32x4{0,0,0,0}; acc[q][1] = f32x4{0,0,0,0}; }
      #pragma unroll
      for (int ks = 0; ks < 4; ++ks){
        int kq = w * 4 + ks;
        s16x8 a0 = ld_coh16B(hG + (size_t)(kq * 64 + l) * 8);
        s16x8 a1 = ld_coh16B(hG + 16384 + (size_t)(kq * 64 + l) * 8);
        s16x8 b0 = *(const s16x8*)(bq0 + ks * 32);
        s16x8 b1 = *(const s16x8*)(bq1 + ks * 32);
        s16x8 b2 = *(const s16x8*)(bq2 + ks * 32);
        s16x8 b3 = *(const s16x8*)(bq3 + ks * 32);
        acc[0][0] = mfma16(a0, b0, acc[0][0]); acc[0][1] = mfma16(a1, b0, acc[0][1]);
        acc[1][0] = mfma16(a0, b1, acc[1][0]); acc[1][1] = mfma16(a1, b1, acc[1][1]);
        acc[2][0] = mfma16(a0, b2, acc[2][0]); acc[2][1] = mfma16(a1, b2, acc[2][1]);
        acc[3][0] = mfma16(a0, b3, acc[3][0]); acc[3][1] = mfma16(a1, b3, acc[3][1]);
      }
      f32x4* accf = (f32x4*)acc;
      // 8-wave tree reduce (payload 8 x f32x4)
      if (w >= 4){
        #pragma unroll
        for (int j = 0; j < 8; j++) *(f32x4*)RSLOT(w - 4, j) = accf[j];
      }
      __syncthreads();
      if (w < 4){
        #pragma unroll
        for (int j = 0; j < 8; j++) accf[j] += *(const f32x4*)RSLOT(w, j);
      }
      __syncthreads();
      if (w == 2 || w == 3){
        #pragma unroll
        for (int j = 0; j < 8; j++) *(f32x4*)RSLOT(w - 2, j) = accf[j];
      }
      __syncthreads();
      if (w < 2){
        #pragma unroll
        for (int j = 0; j < 8; j++) accf[j] += *(const f32x4*)RSLOT(w, j);
      }
      __syncthreads();
      if (w == 1){
        #pragma unroll
        for (int j = 0; j < 8; j++) *(f32x4*)RSLOT(0, j) = accf[j];
      }
      __syncthreads();
      if (w == 0){
        #pragma unroll
        for (int j = 0; j < 8; j++) accf[j] += *(const f32x4*)RSLOT(0, j);
        #pragma unroll
        for (int q = 0; q < 4; q++)
          #pragma unroll
          for (int mf = 0; mf < 2; mf++)
            #pragma unroll
            for (int r = 0; r < 4; r++)
              gatesL[q][mf * 16 + kg * 4 + r][lc] = acc[q][mf][r];
      }
      __syncthreads();
      // owner epilogue
      float pre[4];
      #pragma unroll
      for (int q = 0; q < 4; q++)
        pre[q] = gatesL[q][orow][ocolL] + bgv[q] + gxv[q];
      float ii = sigf(pre[0]), ff = sigf(pre[1]);
      float gt = tanhf_(pre[2]);
      o_reg = sigf(pre[3]);
      c_state = ff * c_state + ii * gt;
      stL[orow][ocolL] = f2bf(c_state);
      oSt[orow][ocolL] = f2bf(o_reg);
      __syncthreads();
      if (tid < 256){
        short* dst = (short*)((tid < 128 ? cG : oG) + poff);
        const short* src = (tid < 128 ? &stL[prr][pci * 4] : &oSt[prr][pci * 4]);
        st_coh_u64(dst, *(const u64*)src);
      }
    }
    gbar(arr, n, ++gen);

    // ---------- PHASE B: e = c~@evo + b (publish bf16), curv -> atomicAdd kp ----------
    {
      f32x4 e0{0,0,0,0}, e1{0,0,0,0};
      if (w < 4){
        #pragma unroll
        for (int ks = 0; ks < 8; ++ks){
          int kq = kh2 * 8 + ks;
          s16x8 a0 = ld_coh16B(cG + (size_t)(kq * 64 + l) * 8);
          s16x8 a1 = ld_coh16B(cG + 16384 + (size_t)(kq * 64 + l) * 8);
          s16x8 bv = *(const s16x8*)(bevo + ks * 32);
          e0 = mfma16(a0, bv, e0); e1 = mfma16(a1, bv, e1);
        }
      } else {
        #pragma unroll
        for (int ks = 0; ks < 8; ++ks){
          int kq = kh2 * 8 + ks;
          s16x8 a0 = ld_coh16B(cG + (size_t)(kq * 64 + l) * 8);
          s16x8 a1 = ld_coh16B(cG + 16384 + (size_t)(kq * 64 + l) * 8);
          s16x8 bv = *(const s16x8*)(bcur + ks * 32);
          e0 = mfma16(a0, bv, e0); e1 = mfma16(a1, bv, e1);
        }
      }
      // two concurrent 4-wave reduces: evo -> slots 0/1, curv -> slots 2/3
      if (w == 2 || w == 3){ *(f32x4*)RSLOT(w - 2, 0) = e0; *(f32x4*)RSLOT(w - 2, 1) = e1; }
      if (w == 6 || w == 7){ *(f32x4*)RSLOT(w - 4, 0) = e0; *(f32x4*)RSLOT(w - 4, 1) = e1; }
      __syncthreads();
      if (w < 2){ e0 += *(const f32x4*)RSLOT(w, 0); e1 += *(const f32x4*)RSLOT(w, 1); }
      if (w == 4 || w == 5){ e0 += *(const f32x4*)RSLOT(w - 2, 0); e1 += *(const f32x4*)RSLOT(w - 2, 1); }
      __syncthreads();
      if (w == 1){ *(f32x4*)RSLOT(0, 0) = e0; *(f32x4*)RSLOT(0, 1) = e1; }
      if (w == 5){ *(f32x4*)RSLOT(2, 0) = e0; *(f32x4*)RSLOT(2, 1) = e1; }
      __syncthreads();
      if (w == 0){
        e0 += *(const f32x4*)RSLOT(0, 0); e1 += *(const f32x4*)RSLOT(0, 1);
        #pragma unroll
        for (int r = 0; r < 4; r++){
          eL[kg * 4 + r][lc]      = e0[r] + ebias;
          eL[16 + kg * 4 + r][lc] = e1[r] + ebias;
        }
      }
      if (w == 4){
        e0 += *(const f32x4*)RSLOT(2, 0); e1 += *(const f32x4*)RSLOT(2, 1);
        #pragma unroll
        for (int mf = 0; mf < 2; mf++){
          #pragma unroll
          for (int r = 0; r < 4; r++){
            float v = fmaxf((mf ? e1[r] : e0[r]) + c1bv, 0.f) * c2wv * cvalid;
            v += __shfl_xor(v, 1); v += __shfl_xor(v, 2);
            v += __shfl_xor(v, 4); v += __shfl_xor(v, 8);
            if (lc == 0)
              at_add_f32(kpg + (mf * 16 + kg * 4 + r) * 8 + (n >> 3), v);
          }
        }
      }
      __syncthreads();
      // publish e (bf16) from eL
      if (tid < 128){
        union { u64 q; short s[4]; } up;
        #pragma unroll
        for (int j = 0; j < 4; j++) up.s[j] = f2bf(eL[prr][pci * 4 + j]);
        st_coh_u64((void*)(eG + poff), up.q);
      }
    }
    gbar(arr, n, ++gen);

    // ---------- PHASE C: kap; m = o*tanh(c~ + DT*kap*e) on the fly; h = tanh(m@mir+b) ----------
    {
      // kap gather
      if (tid < 128){
        union { u64 q; float f[2]; } u;
        u.q = ld_coh_u64(kpg + prr * 8 + pci * 2);
        kpart[prr][pci] = u.f[0] + u.f[1];
      }
      __syncthreads();
      if (tid < 32)
        kapL[tid] = CHI_ * (kpart[tid][0] + kpart[tid][1] + kpart[tid][2] + kpart[tid][3] + cb2v);
      __syncthreads();
      // owner state update
      {
        float e = eL[orow][ocolL];
        c_state = c_state + DT_ * kapL[orow] * e;
        if (t == S_ - 1) dout[OUT_C + oidx] = c_state;
        if (lt == CH - 1) cf32[oidx] = c_state;
      }
      const float k0 = kapL[lc], k1 = kapL[16 + lc];
      f32x4 h0{0,0,0,0}, h1{0,0,0,0};
      #pragma unroll
      for (int ks = 0; ks < 4; ++ks){
        const size_t off = (size_t)((w * 4 + ks) * 64 + l) * 8;
        s16x8 cf0 = ld_coh16B(cG + off), cf1 = ld_coh16B(cG + 16384 + off);
        s16x8 ef0 = ld_coh16B(eG + off), ef1 = ld_coh16B(eG + 16384 + off);
        s16x8 of0 = ld_coh16B(oG + off), of1 = ld_coh16B(oG + 16384 + off);
        s16x8 m0, m1;
        #pragma unroll
        for (int j = 0; j < 8; j++){
          m0[j] = f2bf(b2f(of0[j]) * tanhf_(b2f(cf0[j]) + DT_ * k0 * b2f(ef0[j])));
          m1[j] = f2bf(b2f(of1[j]) * tanhf_(b2f(cf1[j]) + DT_ * k1 * b2f(ef1[j])));
        }
        s16x8 bv = *(const s16x8*)(bmir + ks * 32);
        h0 = mfma16(m0, bv, h0);
        h1 = mfma16(m1, bv, h1);
      }
      // 8-wave tree reduce (payload 2 x f32x4)
      if (w >= 4){ *(f32x4*)RSLOT(w - 4, 0) = h0; *(f32x4*)RSLOT(w - 4, 1) = h1; }
      __syncthreads();
      if (w < 4){ h0 += *(const f32x4*)RSLOT(w, 0); h1 += *(const f32x4*)RSLOT(w, 1); }
      __syncthreads();
      if (w == 2 || w == 3){ *(f32x4*)RSLOT(w - 2, 0) = h0; *(f32x4*)RSLOT(w - 2, 1) = h1; }
      __syncthreads();
      if (w < 2){ h0 += *(const f32x4*)RSLOT(w, 0); h1 += *(const f32x4*)RSLOT(w, 1); }
      __syncthreads();
      if (w == 1){ *(f32x4*)RSLOT(0, 0) = h0; *(f32x4*)RSLOT(0, 1) = h1; }
      __syncthreads();
      if (w == 0){
        h0 += *(const f32x4*)RSLOT(0, 0); h1 += *(const f32x4*)RSLOT(0, 1);
        #pragma unroll
        for (int mf = 0; mf < 2; mf++){
          #pragma unroll
          for (int r = 0; r < 4; r++){
            int row = mf * 16 + kg * 4 + r;
            float hv = tanhf_((mf ? h1[r] : h0[r]) + mirbv);
            hv = hv / (1.f + KAPPA_ * fabsf(hv));
            hfL[row][lc] = hv;
            stL[row][lc] = f2bf(hv);
          }
        }
      }
      __syncthreads();
      // distributed, coalesced dout writes (f32 precision from hfL)
      {
        int rr = tid >> 4, cc = tid & 15;
        float hv = hfL[rr][cc];
        dout[(size_t)(g * 32 + rr) * 524288 + (size_t)t * 1024 + n * 16 + cc] = hv;
        if (t == S_ - 1) dout[OUT_H + (size_t)(g * 32 + rr) * 1024 + n * 16 + cc] = hv;
      }
      if (tid < 128)
        st_coh_u64((void*)(hG + poff), *(const u64*)&stL[prr][pci * 4]);
    }
    gbar(arr, n, ++gen);
  }
}

// ---------- host ----------
extern "C" void kernel_launch(void* const* d_in, const int* in_sizes, int n_in,
                              void* d_out, int out_size, void* d_ws, size_t ws_size,
                              hipStream_t stream)
{
  (void)in_sizes; (void)n_in; (void)out_size; (void)ws_size;
  const float* x   = (const float*)d_in[0];
  const float* Wg  = (const float*)d_in[1];
  const float* bg  = (const float*)d_in[2];
  const float* miW = (const float*)d_in[3];
  const float* mib = (const float*)d_in[4];
  const float* c1W = (const float*)d_in[5];
  const float* c1b = (const float*)d_in[6];
  const float* c2W = (const float*)d_in[7];
  const float* c2b = (const float*)d_in[8];
  const float* evW = (const float*)d_in[9];
  const float* evb = (const float*)d_in[10];
  const float* zw  = (const float*)d_in[11];
  const float* zp  = (const float*)d_in[12];
  float* out = (float*)d_out;
  char* ws = (char*)d_ws;

  unsigned int* cnt = (unsigned int*)(ws + WS_CNT);
  short* hbf  = (short*)(ws + WS_HBF);
  float* cf32 = (float*)(ws + WS_CF32);
  short* cbf  = (short*)(ws + WS_CBF);
  short* obf  = (short*)(ws + WS_OBF);
  short* ebf  = (short*)(ws + WS_EBF);
  float* kpb  = (float*)(ws + WS_KP);
  short* wgT  = (short*)(ws + WS_WGT);
  short* evoT = (short*)(ws + WS_EVOT);
  short* mirT = (short*)(ws + WS_MIRT);
  short* c1T  = (short*)(ws + WS_C1T);
  short* xbf  = (short*)(ws + WS_XBF);
  short* gxc  = (short*)(ws + WS_GXC);

  // reset state: flags, h=0, c'=0
  hipMemsetAsync(ws, 0, WS_STATE_BYTES, stream);

  // weight transposes (fp32 -> bf16, N-major)
  transpose_bf<<<dim3(4096/32, 2048/32), 256, 0, stream>>>(Wg,  wgT, 2048, 4096);
  transpose_bf<<<dim3(1024/32, 1024/32), 256, 0, stream>>>(evW, evoT, 1024, 1024);
  transpose_bf<<<dim3(1024/32, 1024/32), 256, 0, stream>>>(miW, mirT, 1024, 1024);
  transpose_bf<<<dim3(512/32, 1024/32),  256, 0, stream>>>(c1W, c1T, 1024, 512);

  zeta_k<<<1, 64, 0, stream>>>(zw, zp, out + OUT_Z);

  for (int ch = 0; ch < NCHUNK; ++ch){
    conv_x<<<dim3(CH * 128), 256, 0, stream>>>(x, xbf, ch * CH);
    gemm_gx<<<dim3(32, CH), 256, 0, stream>>>(xbf, wgT, gxc);
    scan_k<<<dim3(256), 512, 0, stream>>>(wgT, evoT, mirT, c1T, gxc,
                                          bg, evb, mib, c1b, c2W, c2b,
                                          hbf, cbf, obf, ebf, cf32, kpb,
                                          cnt, out, ch * CH);
  }
}

// Round 6
// 11953.169 us; speedup vs baseline: 1.5179x; 1.5179x over previous
//
#include <hip/hip_runtime.h>
#include <hip/hip_bf16.h>
#include <math.h>
#include <stdint.h>

// ---------- problem constants ----------
#define B_    128
#define S_    512
#define IN_   1024
#define HID_  1024
#define CHI_  0.638f
#define KAPPA_ 0.35f
#define DT_   0.01f
#define CH    32            // timesteps per chunk
#define NCHUNK (S_/CH)      // 16

// output offsets (floats)
#define OUT_H 67108864
#define OUT_C 67239936
#define OUT_Z 67371008

// ---------- ws layout (bytes) ----------
// state buffers use fragment-major "hF16" layout per 16-row group (32KB):
//   [kq 0..31][lane 0..63][16B];  element (r,k): kq=k>>5, lane=((k>>3)&3)*16+r, byte=(k&7)*2
// block n's 32 cols == exactly kq=n -> publish is one contiguous 1KB line.
#define WS_CNT   0                         // 8 groups x 64 u32 arrive flags
#define WS_KP    2048                      // kap partials [8 groups][16 rows][8 slots] f32
#define WS_HBF   6144                      // h  hF16 [8 groups][32KB]
#define WS_CF32  268288                    // c' f32 [128][1024] (chunk-boundary persistence)
#define WS_STATE_BYTES 792576              // CNT+KP+HBF+CF32 zeroed at start
#define WS_CBF   792576                    // c~ hF16
#define WS_MBF   1054720                   // m  hF16
#define WS_WGT   1316864                   // WgT bf16 [4096][2048]
#define WS_EVOT  18094080                  // evoT bf16 [1024][1024]
#define WS_MIRT  20191232                  // mirT bf16 [1024][1024]
#define WS_C1T   22288384                  // c1T bf16 [512][1024]
#define WS_XBF   23336960                  // x chunk bf16 [32*128][1024]
#define WS_GXC   31725568                  // gx chunk bf16 [32][8][4096][16]
// total ~65.3 MB

using s16x8 = __attribute__((ext_vector_type(8))) short;
using s16x4 = __attribute__((ext_vector_type(4))) short;
using f32x4 = __attribute__((ext_vector_type(4))) float;
typedef unsigned long long u64;

static __device__ __forceinline__ short f2bf(float x){
  unsigned int u = __float_as_uint(x);
  u = (u + 0x7FFFu + ((u >> 16) & 1u)) >> 16;
  return (short)u;
}
static __device__ __forceinline__ float b2f(short s){
  return __uint_as_float(((unsigned int)(unsigned short)s) << 16);
}
static __device__ __forceinline__ float sigf(float x){
  return 1.f / (1.f + __expf(-x));
}
static __device__ __forceinline__ float tanhf_(float x){
  return 1.f - 2.f / (__expf(2.f * x) + 1.f);
}
static __device__ __forceinline__ f32x4 mfma16(s16x8 a, s16x8 b, f32x4 c){
  return __builtin_amdgcn_mfma_f32_16x16x32_bf16(a, b, c, 0, 0, 0);
}

// ---------- coherent (device-scope, L2-bypassing) access helpers ----------
static __device__ __forceinline__ u64 ld_coh_u64(const void* p){
  return __hip_atomic_load((const u64*)p, __ATOMIC_RELAXED, __HIP_MEMORY_SCOPE_AGENT);
}
static __device__ __forceinline__ void st_coh_u64(void* p, u64 v){
  __hip_atomic_store((u64*)p, v, __ATOMIC_RELAXED, __HIP_MEMORY_SCOPE_AGENT);
}
static __device__ __forceinline__ float ld_coh_f32(const float* p){
  return __hip_atomic_load(p, __ATOMIC_RELAXED, __HIP_MEMORY_SCOPE_AGENT);
}
static __device__ __forceinline__ void st_coh_f32(float* p, float v){
  __hip_atomic_store(p, v, __ATOMIC_RELAXED, __HIP_MEMORY_SCOPE_AGENT);
}
static __device__ __forceinline__ unsigned ld_coh_u32(const unsigned* p){
  return __hip_atomic_load(p, __ATOMIC_RELAXED, __HIP_MEMORY_SCOPE_AGENT);
}
static __device__ __forceinline__ void st_coh_u32(unsigned* p, unsigned v){
  __hip_atomic_store(p, v, __ATOMIC_RELAXED, __HIP_MEMORY_SCOPE_AGENT);
}
static __device__ __forceinline__ void at_add_f32(float* p, float v){
  __hip_atomic_fetch_add(p, v, __ATOMIC_RELAXED, __HIP_MEMORY_SCOPE_AGENT);
}
static __device__ __forceinline__ s16x8 ld_coh16B(const short* p){
  union { u64 q[2]; s16x8 v; } u;
  u.q[0] = ld_coh_u64(p);
  u.q[1] = ld_coh_u64(p + 4);
  return u.v;
}

// flag barrier: block n stores gen to its own flag; lanes 0..31 poll 32 flags.
static __device__ __forceinline__ void gbar(unsigned* arr, int n, unsigned gen){
  asm volatile("s_waitcnt vmcnt(0)" ::: "memory");
  __syncthreads();
  if (threadIdx.x < 32){
    if (threadIdx.x == 0) st_coh_u32(arr + n, gen);
    unsigned v = ld_coh_u32(arr + threadIdx.x);
    while (!__all(v >= gen)){
      __builtin_amdgcn_s_sleep(2);
      v = ld_coh_u32(arr + threadIdx.x);
    }
  }
  __syncthreads();
}

// ---------- prep kernels ----------
__global__ void transpose_bf(const float* __restrict__ in, short* __restrict__ out,
                             int R, int C){
  __shared__ float tile[32][33];
  int c0 = blockIdx.x * 32, r0 = blockIdx.y * 32;
  int tc = threadIdx.x & 31, tr = threadIdx.x >> 5;   // tr 0..7
  #pragma unroll
  for (int i = 0; i < 4; i++){
    int r = tr + i * 8;
    tile[r][tc] = in[(size_t)(r0 + r) * C + (c0 + tc)];
  }
  __syncthreads();
  #pragma unroll
  for (int i = 0; i < 4; i++){
    int cc = tr + i * 8;
    out[(size_t)(c0 + cc) * R + (r0 + tc)] = f2bf(tile[tc][cc]);
  }
}

__global__ void conv_x(const float* __restrict__ x, short* __restrict__ xbf, int t0){
  int rb = blockIdx.x;                 // rb = tl*128 + b
  int tl = rb >> 7, b = rb & 127;
  const float* src = x + ((size_t)b * S_ + (t0 + tl)) * (size_t)IN_;
  short* dst = xbf + (size_t)rb * IN_;
  int i = threadIdx.x * 4;
  float4 v = *(const float4*)(src + i);
  s16x4 o; o[0]=f2bf(v.x); o[1]=f2bf(v.y); o[2]=f2bf(v.z); o[3]=f2bf(v.w);
  *(s16x4*)(dst + i) = o;
}

// gx chunk GEMM: A = xbf [4096][1024] bf16 (m = tl*128+b), B = WgT[:, 0:1024]
// C written as gxc[tl][g=b>>4][gatecol][b&15] bf16
__global__ __launch_bounds__(256, 2) void gemm_gx(const short* __restrict__ Ax,
                                                  const short* __restrict__ wgT,
                                                  short* __restrict__ gxc){
  __shared__ short As[128 * 32];
  __shared__ short Bs[128 * 32];
  const int tid = threadIdx.x, w = tid >> 6, l = tid & 63;
  const int wm = w & 1, wn = w >> 1;
  const int bn = blockIdx.x, bm = blockIdx.y;
  const int lc = l & 15, kg = l >> 4;
  f32x4 acc[4][4];
  #pragma unroll
  for (int i = 0; i < 4; i++)
    #pragma unroll
    for (int j = 0; j < 4; j++) acc[i][j] = f32x4{0.f, 0.f, 0.f, 0.f};

  const int srow = tid >> 1;
  const int so = (tid & 1) * 32;   // byte offset within 64B row
  const short* ga = Ax  + (size_t)(bm * 128 + srow) * 1024 + (so >> 1);
  const short* gb = wgT + (size_t)(bn * 128 + srow) * 2048 + (so >> 1);
  const int sp0 = srow * 64 + ((so)      ^ ((srow & 3) << 4));
  const int sp1 = srow * 64 + ((so + 16) ^ ((srow & 3) << 4));

  uint4 ra0, ra1, rb0, rb1;
  auto LD = [&](int kt){
    ra0 = *(const uint4*)(ga + kt * 32);
    ra1 = *(const uint4*)(ga + kt * 32 + 8);
    rb0 = *(const uint4*)(gb + kt * 32);
    rb1 = *(const uint4*)(gb + kt * 32 + 8);
  };
  LD(0);
  for (int kt = 0; kt < 32; ++kt){
    __syncthreads();
    *(uint4*)((char*)As + sp0) = ra0;
    *(uint4*)((char*)As + sp1) = ra1;
    *(uint4*)((char*)Bs + sp0) = rb0;
    *(uint4*)((char*)Bs + sp1) = rb1;
    __syncthreads();
    if (kt + 1 < 32) LD(kt + 1);
    s16x8 af[4], bfr[4];
    #pragma unroll
    for (int mf = 0; mf < 4; ++mf){
      int row = wm * 64 + mf * 16 + lc;
      af[mf] = *(const s16x8*)((const char*)As + row * 64 + ((kg * 16) ^ ((row & 3) << 4)));
    }
    #pragma unroll
    for (int nf = 0; nf < 4; ++nf){
      int row = wn * 64 + nf * 16 + lc;
      bfr[nf] = *(const s16x8*)((const char*)Bs + row * 64 + ((kg * 16) ^ ((row & 3) << 4)));
    }
    #pragma unroll
    for (int mf = 0; mf < 4; ++mf)
      #pragma unroll
      for (int nf = 0; nf < 4; ++nf)
        acc[mf][nf] = mfma16(af[mf], bfr[nf], acc[mf][nf]);
  }
  // epilogue: gxc[tl=bm][g][gc][brow] ; g = (wm*64+mf*16)>>4, brow = kg*4..+3
  #pragma unroll
  for (int mf = 0; mf < 4; ++mf){
    #pragma unroll
    for (int nf = 0; nf < 4; ++nf){
      int gg = wm * 4 + mf;
      int gc = bn * 128 + wn * 64 + nf * 16 + lc;
      s16x4 pk;
      #pragma unroll
      for (int r = 0; r < 4; r++) pk[r] = f2bf(acc[mf][nf][r]);
      *(s16x4*)(gxc + (((size_t)bm * 8 + gg) * 4096 + gc) * 16 + kg * 4) = pk;
    }
  }
}

// ---------- zeta ----------
struct cpx { double r, i; };
static __device__ cpx cexp_(cpx z){ double e = exp(z.r); return {e * cos(z.i), e * sin(z.i)}; }
static __device__ cpx xi_(double sr, double si, const float* zw, const float* zp){
  cpx acc{0.0, 0.0};
  for (int i = 0; i < 6; i++){
    double L = 0.2 + 0.1 * i;
    double sw = 1.0 / (1.0 + exp(-(double)zw[i]));
    double sp = 1.0 / (1.0 + exp(-(double)zp[i]));
    cpx t1 = cexp_({-sr * L, -si * L});
    cpx t2 = cexp_({-(1.0 - sr) * L, si * L});
    acc.r += sw * 0.5 * (t1.r + sp * t2.r);
    acc.i += sw * 0.5 * (t1.i + sp * t2.i);
  }
  return acc;
}
__global__ void zeta_k(const float* __restrict__ zw, const float* __restrict__ zp,
                       float* __restrict__ dz){
  if (threadIdx.x == 0 && blockIdx.x == 0){
    cpx a = xi_(0.5, -2.0, zw, zp);
    cpx b = xi_(0.5,  2.0, zw, zp);
    double dr = a.r - b.r, di = a.i - b.i;
    dz[0] = (float)(dr * dr + di * di);
  }
}

// reduce scratch access: 16B-aligned XOR-swizzled f32x4 slots
#define RSLOT(slot, j) ((char*)red + (slot) * 8192 + (size_t)l * 128 + (((j) * 16) ^ ((l & 7) << 4)))

// ---------- persistent scan kernel (one chunk of CH steps) ----------
// 8 groups x 16 batch rows; 32 blocks/group (32 cols each); 512 threads; 4 phases/step.
__global__ __launch_bounds__(512, 2) void scan_k(
    const short* __restrict__ wgT, const short* __restrict__ evoT,
    const short* __restrict__ mirT, const short* __restrict__ c1T,
    const short* __restrict__ gxc,
    const float* __restrict__ bg,  const float* __restrict__ evob,
    const float* __restrict__ mirb, const float* __restrict__ cb1,
    const float* __restrict__ cw2, const float* __restrict__ cb2,
    short* __restrict__ hbf, short* __restrict__ cbf, short* __restrict__ mbf,
    float* __restrict__ cf32, float* __restrict__ kp,
    unsigned int* __restrict__ cnt, float* __restrict__ dout, int t0)
{
  const int tid = threadIdx.x;
  const int w = tid >> 6, l = tid & 63;
  const int lc = l & 15, kg = l >> 4;
  const int bi = blockIdx.x;
  const int g = bi >> 5, n = bi & 31;
  unsigned* arr = cnt + g * 64;

  __shared__ float red[4][64][32];      // 32KB reduce scratch (XOR-swizzled)
  __shared__ float gatesL[4][16][33];
  __shared__ float eL[16][33];
  __shared__ float kpart[16][8];
  __shared__ float kapL[16];
  __shared__ short stL[16][32];
  __shared__ float hfL[16][32];

  // hF16 group bases (shorts)
  const short* hG = hbf + (size_t)g * 16384;
  const short* cG = cbf + (size_t)g * 16384;
  const short* mG = mbf + (size_t)g * 16384;
  float* kpg = kp + g * 128;            // [16 rows][8 slots]

  // publish: block owns kq=n (1KB line). thread t<128: l2=t>>1, half=t&1
  // src element: row=l2&15, klocal=(l2>>4)*8+half*4
  const int pl = (tid & 127) >> 1, ph = tid & 1;
  const size_t poff = (size_t)(n * 64 + pl) * 8 + ph * 4;   // shorts
  const int psr = pl & 15, psc = (pl >> 4) * 8 + ph * 4;

  // owner mapping: thread -> (row = tid>>5, colL = tid&31), col = n*32+colL
  const int orow = tid >> 5, ocolL = tid & 31;
  const int ocol = n * 32 + ocolL;
  const size_t oidx = (size_t)(g * 16 + orow) * HID_ + ocol;
  float c_state = cf32[oidx];
  float o_reg = 0.f;
  float bgv[4];
  #pragma unroll
  for (int q = 0; q < 4; q++) bgv[q] = bg[q * 1024 + ocol];
  const float cb2v = cb2[0];

  // B-operand pointers (normal cached loads, L2-resident per XCD)
  const short* bqp[4][2];
  #pragma unroll
  for (int q = 0; q < 4; q++)
    #pragma unroll
    for (int cf = 0; cf < 2; cf++)
      bqp[q][cf] = wgT + (size_t)(q * 1024 + n * 32 + cf * 16 + lc) * 2048 + 1024 + w * 128 + kg * 8;
  const short* bevo0 = evoT + (size_t)(n * 32 + lc) * 1024 + w * 128 + kg * 8;
  const short* bevo1 = bevo0 + 16 * 1024;
  const short* bcur  = c1T + (size_t)(n * 16 + lc) * 1024 + w * 128 + kg * 8;
  const short* bmir0 = mirT + (size_t)(n * 32 + lc) * 1024 + w * 128 + kg * 8;
  const short* bmir1 = bmir0 + 16 * 1024;
  const float eb0 = evob[n * 32 + lc], eb1 = evob[n * 32 + 16 + lc];
  const float c1bv = cb1[n * 16 + lc], c2wv = cw2[n * 16 + lc];
  const float mb0 = mirb[n * 32 + lc], mb1 = mirb[n * 32 + 16 + lc];

  unsigned gen = (unsigned)t0 * 4;

  for (int lt = 0; lt < CH; ++lt){
    const int t = t0 + lt;

    // gx prefetch (normal loads)
    float gxv[4];
    #pragma unroll
    for (int q = 0; q < 4; q++)
      gxv[q] = b2f(gxc[(((size_t)lt * 8 + g) * 4096 + q * 1024 + ocol) * 16 + orow]);

    // ---------- PHASE A: gates = gx + h @ Wh + b; c~, o; publish c~ ----------
    {
      f32x4 acc[4][2];
      #pragma unroll
      for (int q = 0; q < 4; q++){ acc[q][0] = f32x4{0,0,0,0}; acc[q][1] = f32x4{0,0,0,0}; }
      #pragma unroll
      for (int ks = 0; ks < 4; ++ks){
        int kq = w * 4 + ks;
        s16x8 a = ld_coh16B(hG + (size_t)(kq * 64 + l) * 8);
        #pragma unroll
        for (int q = 0; q < 4; q++){
          s16x8 b0 = *(const s16x8*)(bqp[q][0] + ks * 32);
          s16x8 b1 = *(const s16x8*)(bqp[q][1] + ks * 32);
          acc[q][0] = mfma16(a, b0, acc[q][0]);
          acc[q][1] = mfma16(a, b1, acc[q][1]);
        }
      }
      f32x4* accf = (f32x4*)acc;
      // 8-wave tree reduce (payload 8 x f32x4)
      if (w >= 4){
        #pragma unroll
        for (int j = 0; j < 8; j++) *(f32x4*)RSLOT(w - 4, j) = accf[j];
      }
      __syncthreads();
      if (w < 4){
        #pragma unroll
        for (int j = 0; j < 8; j++) accf[j] += *(const f32x4*)RSLOT(w, j);
      }
      __syncthreads();
      if (w == 2 || w == 3){
        #pragma unroll
        for (int j = 0; j < 8; j++) *(f32x4*)RSLOT(w - 2, j) = accf[j];
      }
      __syncthreads();
      if (w < 2){
        #pragma unroll
        for (int j = 0; j < 8; j++) accf[j] += *(const f32x4*)RSLOT(w, j);
      }
      __syncthreads();
      if (w == 1){
        #pragma unroll
        for (int j = 0; j < 8; j++) *(f32x4*)RSLOT(0, j) = accf[j];
      }
      __syncthreads();
      if (w == 0){
        #pragma unroll
        for (int j = 0; j < 8; j++) accf[j] += *(const f32x4*)RSLOT(0, j);
        #pragma unroll
        for (int q = 0; q < 4; q++)
          #pragma unroll
          for (int cf = 0; cf < 2; cf++)
            #pragma unroll
            for (int r = 0; r < 4; r++)
              gatesL[q][kg * 4 + r][cf * 16 + lc] = acc[q][cf][r];
      }
      __syncthreads();
      // owner epilogue
      float pre[4];
      #pragma unroll
      for (int q = 0; q < 4; q++)
        pre[q] = gatesL[q][orow][ocolL] + bgv[q] + gxv[q];
      float ii = sigf(pre[0]), ff = sigf(pre[1]);
      float gt = tanhf_(pre[2]);
      o_reg = sigf(pre[3]);
      c_state = ff * c_state + ii * gt;
      stL[orow][ocolL] = f2bf(c_state);
      __syncthreads();
      if (tid < 128)
        st_coh_u64((void*)(cG + poff), *(const u64*)&stL[psr][psc]);
    }
    gbar(arr, n, ++gen);

    // ---------- PHASE B: e = c~@evo + b (LDS-local), curv -> atomicAdd kp ----------
    {
      f32x4 e0{0,0,0,0}, e1{0,0,0,0}, cv{0,0,0,0};
      #pragma unroll
      for (int ks = 0; ks < 4; ++ks){
        int kq = w * 4 + ks;
        s16x8 a = ld_coh16B(cG + (size_t)(kq * 64 + l) * 8);
        s16x8 b0 = *(const s16x8*)(bevo0 + ks * 32);
        s16x8 b1 = *(const s16x8*)(bevo1 + ks * 32);
        s16x8 bc = *(const s16x8*)(bcur + ks * 32);
        e0 = mfma16(a, b0, e0);
        e1 = mfma16(a, b1, e1);
        cv = mfma16(a, bc, cv);
      }
      // 8-wave tree reduce (payload 3 x f32x4)
      if (w >= 4){
        *(f32x4*)RSLOT(w - 4, 0) = e0; *(f32x4*)RSLOT(w - 4, 1) = e1; *(f32x4*)RSLOT(w - 4, 2) = cv;
      }
      __syncthreads();
      if (w < 4){
        e0 += *(const f32x4*)RSLOT(w, 0); e1 += *(const f32x4*)RSLOT(w, 1); cv += *(const f32x4*)RSLOT(w, 2);
      }
      __syncthreads();
      if (w == 2 || w == 3){
        *(f32x4*)RSLOT(w - 2, 0) = e0; *(f32x4*)RSLOT(w - 2, 1) = e1; *(f32x4*)RSLOT(w - 2, 2) = cv;
      }
      __syncthreads();
      if (w < 2){
        e0 += *(const f32x4*)RSLOT(w, 0); e1 += *(const f32x4*)RSLOT(w, 1); cv += *(const f32x4*)RSLOT(w, 2);
      }
      __syncthreads();
      if (w == 1){
        *(f32x4*)RSLOT(0, 0) = e0; *(f32x4*)RSLOT(0, 1) = e1; *(f32x4*)RSLOT(0, 2) = cv;
      }
      __syncthreads();
      if (w == 0){
        e0 += *(const f32x4*)RSLOT(0, 0); e1 += *(const f32x4*)RSLOT(0, 1); cv += *(const f32x4*)RSLOT(0, 2);
        #pragma unroll
        for (int r = 0; r < 4; r++){
          eL[kg * 4 + r][lc]      = e0[r] + eb0;
          eL[kg * 4 + r][16 + lc] = e1[r] + eb1;
          float v = fmaxf(cv[r] + c1bv, 0.f) * c2wv;
          v += __shfl_xor(v, 1); v += __shfl_xor(v, 2);
          v += __shfl_xor(v, 4); v += __shfl_xor(v, 8);
          if (lc == 0)
            at_add_f32(kpg + (kg * 4 + r) * 8 + (n >> 2), v);
        }
      }
    }
    gbar(arr, n, ++gen);

    // ---------- PHASE C (tiny): kap; owner m = o*tanh(c'); publish m ----------
    {
      if (tid < 128)
        kpart[tid >> 3][tid & 7] = ld_coh_f32(kpg + tid);
      __syncthreads();
      if (tid < 16){
        float s = 0.f;
        #pragma unroll
        for (int j = 0; j < 8; j++) s += kpart[tid][j];
        kapL[tid] = CHI_ * (s + cb2v);
      }
      __syncthreads();
      {
        float e = eL[orow][ocolL];
        c_state = c_state + DT_ * kapL[orow] * e;
        float mm = o_reg * tanhf_(c_state);
        stL[orow][ocolL] = f2bf(mm);
        if (t == S_ - 1) dout[OUT_C + oidx] = c_state;
        if (lt == CH - 1) cf32[oidx] = c_state;
      }
      __syncthreads();
      if (tid < 128)
        st_coh_u64((void*)(mG + poff), *(const u64*)&stL[psr][psc]);
    }
    gbar(arr, n, ++gen);

    // ---------- PHASE D: h = tanh(m @ mirror + b); h /= 1+k|h|; publish h ----------
    {
      f32x4 h0{0,0,0,0}, h1{0,0,0,0};
      #pragma unroll
      for (int ks = 0; ks < 4; ++ks){
        int kq = w * 4 + ks;
        s16x8 a = ld_coh16B(mG + (size_t)(kq * 64 + l) * 8);
        s16x8 b0 = *(const s16x8*)(bmir0 + ks * 32);
        s16x8 b1 = *(const s16x8*)(bmir1 + ks * 32);
        h0 = mfma16(a, b0, h0);
        h1 = mfma16(a, b1, h1);
      }
      // 8-wave tree reduce (payload 2 x f32x4)
      if (w >= 4){ *(f32x4*)RSLOT(w - 4, 0) = h0; *(f32x4*)RSLOT(w - 4, 1) = h1; }
      __syncthreads();
      if (w < 4){ h0 += *(const f32x4*)RSLOT(w, 0); h1 += *(const f32x4*)RSLOT(w, 1); }
      __syncthreads();
      if (w == 2 || w == 3){ *(f32x4*)RSLOT(w - 2, 0) = h0; *(f32x4*)RSLOT(w - 2, 1) = h1; }
      __syncthreads();
      if (w < 2){ h0 += *(const f32x4*)RSLOT(w, 0); h1 += *(const f32x4*)RSLOT(w, 1); }
      __syncthreads();
      if (w == 1){ *(f32x4*)RSLOT(0, 0) = h0; *(f32x4*)RSLOT(0, 1) = h1; }
      __syncthreads();
      if (w == 0){
        h0 += *(const f32x4*)RSLOT(0, 0); h1 += *(const f32x4*)RSLOT(0, 1);
        #pragma unroll
        for (int cf = 0; cf < 2; cf++){
          #pragma unroll
          for (int r = 0; r < 4; r++){
            int row = kg * 4 + r;
            float hv = tanhf_((cf ? h1[r] : h0[r]) + (cf ? mb1 : mb0));
            hv = hv / (1.f + KAPPA_ * fabsf(hv));
            hfL[row][cf * 16 + lc] = hv;
            stL[row][cf * 16 + lc] = f2bf(hv);
          }
        }
      }
      __syncthreads();
      // distributed, coalesced dout writes
      {
        float hv = hfL[orow][ocolL];
        dout[(size_t)(g * 16 + orow) * 524288 + (size_t)t * 1024 + ocol] = hv;
        if (t == S_ - 1) dout[OUT_H + oidx] = hv;
      }
      if (tid < 128)
        st_coh_u64((void*)(hG + poff), *(const u64*)&stL[psr][psc]);
      // kp re-zero for next step (readers finished before barrier 3)
      if (n == 0 && tid >= 128 && tid < 256)
        st_coh_f32(kpg + (tid - 128), 0.f);
    }
    gbar(arr, n, ++gen);
  }
}

// ---------- host ----------
extern "C" void kernel_launch(void* const* d_in, const int* in_sizes, int n_in,
                              void* d_out, int out_size, void* d_ws, size_t ws_size,
                              hipStream_t stream)
{
  (void)in_sizes; (void)n_in; (void)out_size; (void)ws_size;
  const float* x   = (const float*)d_in[0];
  const float* Wg  = (const float*)d_in[1];
  const float* bg  = (const float*)d_in[2];
  const float* miW = (const float*)d_in[3];
  const float* mib = (const float*)d_in[4];
  const float* c1W = (const float*)d_in[5];
  const float* c1b = (const float*)d_in[6];
  const float* c2W = (const float*)d_in[7];
  const float* c2b = (const float*)d_in[8];
  const float* evW = (const float*)d_in[9];
  const float* evb = (const float*)d_in[10];
  const float* zw  = (const float*)d_in[11];
  const float* zp  = (const float*)d_in[12];
  float* out = (float*)d_out;
  char* ws = (char*)d_ws;

  unsigned int* cnt = (unsigned int*)(ws + WS_CNT);
  float* kpb  = (float*)(ws + WS_KP);
  short* hbf  = (short*)(ws + WS_HBF);
  float* cf32 = (float*)(ws + WS_CF32);
  short* cbf  = (short*)(ws + WS_CBF);
  short* mbf  = (short*)(ws + WS_MBF);
  short* wgT  = (short*)(ws + WS_WGT);
  short* evoT = (short*)(ws + WS_EVOT);
  short* mirT = (short*)(ws + WS_MIRT);
  short* c1T  = (short*)(ws + WS_C1T);
  short* xbf  = (short*)(ws + WS_XBF);
  short* gxc  = (short*)(ws + WS_GXC);

  // reset state: flags, kp, h=0, c'=0
  hipMemsetAsync(ws, 0, WS_STATE_BYTES, stream);

  // weight transposes (fp32 -> bf16, N-major)
  transpose_bf<<<dim3(4096/32, 2048/32), 256, 0, stream>>>(Wg,  wgT, 2048, 4096);
  transpose_bf<<<dim3(1024/32, 1024/32), 256, 0, stream>>>(evW, evoT, 1024, 1024);
  transpose_bf<<<dim3(1024/32, 1024/32), 256, 0, stream>>>(miW, mirT, 1024, 1024);
  transpose_bf<<<dim3(512/32, 1024/32),  256, 0, stream>>>(c1W, c1T, 1024, 512);

  zeta_k<<<1, 64, 0, stream>>>(zw, zp, out + OUT_Z);

  for (int ch = 0; ch < NCHUNK; ++ch){
    conv_x<<<dim3(CH * 128), 256, 0, stream>>>(x, xbf, ch * CH);
    gemm_gx<<<dim3(32, CH), 256, 0, stream>>>(xbf, wgT, gxc);
    scan_k<<<dim3(256), 512, 0, stream>>>(wgT, evoT, mirT, c1T, gxc,
                                          bg, evb, mib, c1b, c2W, c2b,
                                          hbf, cbf, mbf, cf32, kpb,
                                          cnt, out, ch * CH);
  }
}